// Round 1
// baseline (1119.065 us; speedup 1.0000x reference)
//
#include <hip/hip_runtime.h>
#include <math.h>

#define BB 32
#define NN 1024
#define BN (BB*NN)

__device__ __forceinline__ float sigmoidf(float v) { return 1.0f / (1.0f + expf(-v)); }

// ---------------- embedding: emb[row][256] ----------------
__global__ void k_emb(const int* __restrict__ xint, const float* __restrict__ xyz,
                      const float* __restrict__ am, const float* __restrict__ el,
                      const float* __restrict__ po, const float* __restrict__ xw,
                      const float* __restrict__ xb, float* __restrict__ emb) {
  int row = blockIdx.x;     // 0..BN-1
  int d = threadIdx.x;      // 0..255
  int i0 = xint[row*3+0], i1 = xint[row*3+1], i2 = xint[row*3+2];
  float v;
  if (d < 28)        v = am[i0*28 + d];
  else if (d < 56)   v = el[i1*28 + (d-28)];
  else if (d < 84)   v = po[i2*28 + (d-56)];
  else {
    int o = d - 84;
    float x0 = xyz[row*3+0], x1 = xyz[row*3+1], x2 = xyz[row*3+2];
    v = fmaxf(xw[o*3+0]*x0 + xw[o*3+1]*x1 + xw[o*3+2]*x2 + xb[o], 0.0f);
  }
  emb[(size_t)row*256 + d] = v;
}

// ---------------- fp32 GEMM: C[M,Nc] = A[M,K] * W[n*ldw+woff+k]^T + bias ----------------
// tiles 128x128, BK=16, block=256 threads, 8x8 register blocking
__global__ __launch_bounds__(256) void k_gemm(const float* __restrict__ A, int K,
        const float* __restrict__ W, int ldw, int woff,
        const float* __restrict__ bias, float* __restrict__ C, int Nc) {
  __shared__ float As[16][128];
  __shared__ float Bs[16][128];
  const int m0 = blockIdx.x * 128;
  const int n0 = blockIdx.y * 128;
  const int tid = threadIdx.x;
  const int tx = tid & 15, ty = tid >> 4;
  float acc[8][8];
#pragma unroll
  for (int i = 0; i < 8; i++)
#pragma unroll
    for (int j = 0; j < 8; j++) acc[i][j] = 0.0f;

  for (int kt = 0; kt < K; kt += 16) {
#pragma unroll
    for (int i = 0; i < 2; i++) {
      int s = tid + i*256;          // 0..511
      int r = s >> 2;               // 0..127
      int kq = (s & 3) * 4;         // 0,4,8,12
      float4 a4 = *(const float4*)(A + (size_t)(m0 + r)*K + kt + kq);
      As[kq+0][r] = a4.x; As[kq+1][r] = a4.y; As[kq+2][r] = a4.z; As[kq+3][r] = a4.w;
      float4 b4 = *(const float4*)(W + (size_t)(n0 + r)*ldw + woff + kt + kq);
      Bs[kq+0][r] = b4.x; Bs[kq+1][r] = b4.y; Bs[kq+2][r] = b4.z; Bs[kq+3][r] = b4.w;
    }
    __syncthreads();
#pragma unroll
    for (int kk = 0; kk < 16; kk++) {
      float4 a0 = *(const float4*)&As[kk][ty*4];
      float4 a1 = *(const float4*)&As[kk][64 + ty*4];
      float4 b0 = *(const float4*)&Bs[kk][tx*4];
      float4 b1 = *(const float4*)&Bs[kk][64 + tx*4];
      float av[8] = {a0.x,a0.y,a0.z,a0.w,a1.x,a1.y,a1.z,a1.w};
      float bv[8] = {b0.x,b0.y,b0.z,b0.w,b1.x,b1.y,b1.z,b1.w};
#pragma unroll
      for (int i = 0; i < 8; i++)
#pragma unroll
        for (int j = 0; j < 8; j++) acc[i][j] += av[i]*bv[j];
    }
    __syncthreads();
  }
#pragma unroll
  for (int rh = 0; rh < 2; rh++)
#pragma unroll
    for (int i = 0; i < 4; i++) {
      int row = m0 + rh*64 + ty*4 + i;
#pragma unroll
      for (int ch = 0; ch < 2; ch++) {
        int col = n0 + ch*64 + tx*4;
        float4 o;
        o.x = acc[rh*4+i][ch*4+0];
        o.y = acc[rh*4+i][ch*4+1];
        o.z = acc[rh*4+i][ch*4+2];
        o.w = acc[rh*4+i][ch*4+3];
        if (bias) { o.x += bias[col]; o.y += bias[col+1]; o.z += bias[col+2]; o.w += bias[col+3]; }
        *(float4*)(C + (size_t)row*Nc + col) = o;
      }
    }
}

// ---------------- zero h,c ----------------
__global__ void k_zero(float* __restrict__ h, float* __restrict__ c) {
  int i = blockIdx.x * 256 + threadIdx.x;   // 32768
  h[i] = 0.0f; c[i] = 0.0f;
}

// ---------------- mean over n, stage 1: pp[nch][b][o] ----------------
__global__ void k_mean1(const float* __restrict__ x, float* __restrict__ pp) {
  int blk = blockIdx.x;                 // 1024 = b(32) x och(4) x nch(8)
  int b = blk >> 5;
  int rest = blk & 31;
  int och = rest >> 3, nch = rest & 7;
  int o = och*256 + threadIdx.x;
  int n0 = nch*128;
  float acc = 0.0f;
  const float* xb = x + ((size_t)(b*NN + n0))*1024 + o;
  for (int n = 0; n < 128; n++) acc += xb[(size_t)n*1024];
  pp[((size_t)nch*32 + b)*1024 + o] = acc;
}

// ---------------- mean stage 2 -> P ----------------
__global__ void k_mean2(const float* __restrict__ pp, float* __restrict__ P) {
  int idx = blockIdx.x*256 + threadIdx.x;  // 32768
  int b = idx >> 10, o = idx & 1023;
  float s = 0.0f;
  for (int p = 0; p < 8; p++) s += pp[((size_t)p*32 + b)*1024 + o];
  P[idx] = s * (1.0f/1024.0f);
}

// ---------------- gates partials: gp[ks][b][j] ----------------
// K=3072 as [P(1024) | h(1024 via w_ih cols 1024:) | h(1024 via w_hh)]
#define KS 48
#define KCH 64
__global__ __launch_bounds__(256) void k_gates(const float* __restrict__ P, const float* __restrict__ h,
        const float* __restrict__ w_ih, const float* __restrict__ w_hh,
        float* __restrict__ gp) {
  __shared__ float Xs[32][KCH];
  int jb = blockIdx.x / KS;          // 0..7
  int ks = blockIdx.x % KS;          // 0..47
  int tid = threadIdx.x;
  int kglob = ks * KCH;              // 0..3008
  // stage Xs
#pragma unroll
  for (int i = 0; i < 8; i++) {
    int s = tid + i*256;             // 0..2047
    int bb = s >> 6, kk = s & 63;
    float v;
    if (kglob < 1024)       v = P[bb*1024 + kglob + kk];
    else if (kglob < 2048)  v = h[bb*1024 + (kglob - 1024) + kk];
    else                    v = h[bb*1024 + (kglob - 2048) + kk];
    Xs[bb][kk] = v;
  }
  __syncthreads();

  int j0 = jb*512 + tid;
  int j1 = j0 + 256;
  const float* wr0;
  const float* wr1;
  if (kglob < 2048) { wr0 = w_ih + (size_t)j0*2048 + kglob; wr1 = w_ih + (size_t)j1*2048 + kglob; }
  else              { wr0 = w_hh + (size_t)j0*1024 + (kglob - 2048); wr1 = w_hh + (size_t)j1*1024 + (kglob - 2048); }

  float acc0[32], acc1[32];
#pragma unroll
  for (int b = 0; b < 32; b++) { acc0[b] = 0.0f; acc1[b] = 0.0f; }

  for (int kk = 0; kk < KCH; kk += 4) {
    float4 w0 = *(const float4*)(wr0 + kk);
    float4 w1 = *(const float4*)(wr1 + kk);
#pragma unroll
    for (int b = 0; b < 32; b++) {
      float4 xs = *(const float4*)&Xs[b][kk];
      acc0[b] += w0.x*xs.x + w0.y*xs.y + w0.z*xs.z + w0.w*xs.w;
      acc1[b] += w1.x*xs.x + w1.y*xs.y + w1.z*xs.z + w1.w*xs.w;
    }
  }
#pragma unroll
  for (int b = 0; b < 32; b++) {
    gp[((size_t)ks*32 + b)*4096 + j0] = acc0[b];
    gp[((size_t)ks*32 + b)*4096 + j1] = acc1[b];
  }
}

// ---------------- reduce gates, LSTM cell, ra = h . att1_w[:, :1024]^T ----------------
__global__ __launch_bounds__(256) void k_lstm_ra(const float* __restrict__ gp,
        const float* __restrict__ b_ih, const float* __restrict__ b_hh,
        float* __restrict__ c, float* __restrict__ h,
        const float* __restrict__ att1w, float* __restrict__ ra) {
  int b = blockIdx.x;   // 32
  int t = threadIdx.x;  // 256
  __shared__ float G[4096];
  __shared__ float hs[1024];
#pragma unroll
  for (int i = 0; i < 16; i++) {
    int j = t + i*256;
    float s = b_ih[j] + b_hh[j];
    for (int p = 0; p < KS; p++) s += gp[((size_t)p*32 + b)*4096 + j];
    G[j] = s;
  }
  __syncthreads();
#pragma unroll
  for (int i = 0; i < 4; i++) {
    int d = t + i*256;
    float ig = G[d], fg = G[1024+d], gg = G[2048+d], og = G[3072+d];
    float cn = sigmoidf(fg)*c[b*1024+d] + sigmoidf(ig)*tanhf(gg);
    float hn = sigmoidf(og)*tanhf(cn);
    c[b*1024+d] = cn;
    h[b*1024+d] = hn;
    hs[d] = hn;
  }
  __syncthreads();
  if (t < 128) {
    float acc = 0.0f;
    const float* wr = att1w + (size_t)t*2048;
    for (int d = 0; d < 1024; d += 4) {
      float4 w4 = *(const float4*)(wr + d);
      acc += w4.x*hs[d] + w4.y*hs[d+1] + w4.z*hs[d+2] + w4.w*hs[d+3];
    }
    ra[b*128 + t] = acc;
  }
}

// ---------------- logits[b][n] ----------------
__global__ void k_logits(const float* __restrict__ xa, const float* __restrict__ ra,
                         const float* __restrict__ att1b, const float* __restrict__ att2w,
                         const float* __restrict__ att2b, float* __restrict__ lg) {
  int blk = blockIdx.x;            // 128
  int t = threadIdx.x;             // 256
  int row = blk*256 + t;           // b*1024+n
  int b = blk >> 2;
  __shared__ float rb[128], w2[128];
  if (t < 128) { rb[t] = ra[b*128 + t] + att1b[t]; w2[t] = att2w[t]; }
  __syncthreads();
  float acc = att2b[0];
  const float* xr = xa + (size_t)row*128;
  for (int k = 0; k < 128; k += 4) {
    float4 v = *(const float4*)(xr + k);
    acc += fmaxf(v.x + rb[k+0], 0.0f)*w2[k+0]
         + fmaxf(v.y + rb[k+1], 0.0f)*w2[k+1]
         + fmaxf(v.z + rb[k+2], 0.0f)*w2[k+2]
         + fmaxf(v.w + rb[k+3], 0.0f)*w2[k+3];
  }
  lg[row] = acc;
}

// ---------------- per-b softmax stats: stats[b] = {max, 1/sum} ----------------
__global__ void k_rowstats(const float* __restrict__ lg, float* __restrict__ stats) {
  int b = blockIdx.x, t = threadIdx.x;   // 32 x 256
  __shared__ float red[256];
  float mx = -1e30f;
  for (int i = 0; i < 4; i++) mx = fmaxf(mx, lg[b*1024 + t + i*256]);
  red[t] = mx; __syncthreads();
  for (int s = 128; s > 0; s >>= 1) { if (t < s) red[t] = fmaxf(red[t], red[t+s]); __syncthreads(); }
  float m = red[0]; __syncthreads();
  float sum = 0.0f;
  for (int i = 0; i < 4; i++) sum += expf(lg[b*1024 + t + i*256] - m);
  red[t] = sum; __syncthreads();
  for (int s = 128; s > 0; s >>= 1) { if (t < s) red[t] += red[t+s]; __syncthreads(); }
  if (t == 0) { stats[b*2] = m; stats[b*2+1] = 1.0f / red[0]; }
}

// ---------------- pooled stage 1: pp[nch][b][o] ----------------
__global__ void k_pooled1(const float* __restrict__ x, const float* __restrict__ lg,
                          const float* __restrict__ stats, float* __restrict__ pp) {
  int blk = blockIdx.x;            // 1024 = b(32) x och(4) x nch(8)
  int b = blk >> 5;
  int rest = blk & 31;
  int och = rest >> 3, nch = rest & 7;
  int t = threadIdx.x;
  int o = och*256 + t;
  int n0 = nch*128;
  float m = stats[b*2], inv = stats[b*2+1];
  __shared__ float ws[128];
  if (t < 128) ws[t] = expf(lg[b*1024 + n0 + t] - m) * inv;
  __syncthreads();
  float acc = 0.0f;
  const float* xb = x + ((size_t)(b*NN + n0))*1024 + o;
  for (int n = 0; n < 128; n++) acc += ws[n] * xb[(size_t)n*1024];
  pp[((size_t)nch*32 + b)*1024 + o] = acc;
}

// ---------------- pooled stage 2 -> P ----------------
__global__ void k_pooled2(const float* __restrict__ pp, float* __restrict__ P) {
  int idx = blockIdx.x*256 + threadIdx.x;  // 32768
  int b = idx >> 10, o = idx & 1023;
  float s = 0.0f;
  for (int p = 0; p < 8; p++) s += pp[((size_t)p*32 + b)*1024 + o];
  P[idx] = s;
}

// ---------------- final energy ----------------
__global__ void k_out(const float* __restrict__ c, const float* __restrict__ ew,
                      const float* __restrict__ eb, float* __restrict__ out) {
  int b = blockIdx.x, t = threadIdx.x;   // 32 x 64
  float acc = 0.0f;
  for (int d = t; d < 1024; d += 64) acc += c[b*1024 + d] * ew[d];
  for (int off = 32; off > 0; off >>= 1) acc += __shfl_down(acc, off, 64);
  if (t == 0) out[b] = acc + eb[0];
}

extern "C" void kernel_launch(void* const* d_in, const int* in_sizes, int n_in,
                              void* d_out, int out_size, void* d_ws, size_t ws_size,
                              hipStream_t stream) {
  const int*   x_int  = (const int*)d_in[0];
  const float* x_xyz  = (const float*)d_in[1];
  const float* am     = (const float*)d_in[2];
  const float* el     = (const float*)d_in[3];
  const float* po     = (const float*)d_in[4];
  const float* xyz_w  = (const float*)d_in[5];
  const float* xyz_b  = (const float*)d_in[6];
  const float* up_w   = (const float*)d_in[7];
  const float* up_b   = (const float*)d_in[8];
  const float* w_ih   = (const float*)d_in[9];
  const float* w_hh   = (const float*)d_in[10];
  const float* b_ih   = (const float*)d_in[11];
  const float* b_hh   = (const float*)d_in[12];
  const float* att1_w = (const float*)d_in[13];
  const float* att1_b = (const float*)d_in[14];
  const float* att2_w = (const float*)d_in[15];
  const float* att2_b = (const float*)d_in[16];
  const float* en_w   = (const float*)d_in[17];
  const float* en_b   = (const float*)d_in[18];
  float* out = (float*)d_out;

  char* ws = (char*)d_ws;
  size_t off = 0;
  auto alloc = [&](size_t bytes) { void* p = ws + off; off += (bytes + 255) & ~(size_t)255; return p; };
  float* emb = (float*)alloc((size_t)BN*256*4);        // 33.6 MB
  float* x   = (float*)alloc((size_t)BN*1024*4);       // 134 MB
  float* xa  = (float*)alloc((size_t)BN*128*4);        // 16.8 MB
  float* gp  = (float*)alloc((size_t)KS*32*4096*4);    // 25.2 MB
  float* pp  = (float*)alloc((size_t)8*32*1024*4);     // 1 MB
  float* P   = (float*)alloc((size_t)32*1024*4);
  float* h   = (float*)alloc((size_t)32*1024*4);
  float* c   = (float*)alloc((size_t)32*1024*4);
  float* ra  = (float*)alloc((size_t)32*128*4);
  float* lg  = (float*)alloc((size_t)32*1024*4);
  float* st  = (float*)alloc((size_t)32*2*4);
  (void)ws_size; (void)in_sizes; (void)n_in; (void)out_size;

  k_zero<<<128, 256, 0, stream>>>(h, c);
  k_emb<<<BN, 256, 0, stream>>>(x_int, x_xyz, am, el, po, xyz_w, xyz_b, emb);
  // x = emb @ up_w^T + up_b   (M=32768, K=256, N=1024)
  k_gemm<<<dim3(BN/128, 1024/128), 256, 0, stream>>>(emb, 256, up_w, 256, 0, up_b, x, 1024);
  // xa = x @ att1_w[:,1024:]^T  (M=32768, K=1024, N=128), no bias
  k_gemm<<<dim3(BN/128, 1), 256, 0, stream>>>(x, 1024, att1_w, 2048, 1024, nullptr, xa, 128);
  // P = mean over n of x
  k_mean1<<<1024, 256, 0, stream>>>(x, pp);
  k_mean2<<<128, 256, 0, stream>>>(pp, P);

  for (int step = 0; step < 6; step++) {
    k_gates<<<8*KS, 256, 0, stream>>>(P, h, w_ih, w_hh, gp);
    k_lstm_ra<<<32, 256, 0, stream>>>(gp, b_ih, b_hh, c, h, att1_w, ra);
    if (step < 5) {  // last step's attention output is unused (only c feeds the energy head)
      k_logits<<<128, 256, 0, stream>>>(xa, ra, att1_b, att2_w, att2_b, lg);
      k_rowstats<<<32, 256, 0, stream>>>(lg, st);
      k_pooled1<<<1024, 256, 0, stream>>>(x, lg, st, pp);
      k_pooled2<<<128, 256, 0, stream>>>(pp, P);
    }
  }
  k_out<<<32, 64, 0, stream>>>(c, en_w, en_b, out);
}

// Round 2
// 640.361 us; speedup vs baseline: 1.7476x; 1.7476x over previous
//
#include <hip/hip_runtime.h>
#include <math.h>

#define BB 32
#define NN 1024
#define BN (BB*NN)
#define KS 24
#define KCH 128

__device__ __forceinline__ float sigmoidf(float v) { return 1.0f / (1.0f + expf(-v)); }

// ---------------- embedding: emb[row][256] ----------------
__global__ void k_emb(const int* __restrict__ xint, const float* __restrict__ xyz,
                      const float* __restrict__ am, const float* __restrict__ el,
                      const float* __restrict__ po, const float* __restrict__ xw,
                      const float* __restrict__ xb, float* __restrict__ emb) {
  int row = blockIdx.x;     // 0..BN-1
  int d = threadIdx.x;      // 0..255
  int i0 = xint[row*3+0], i1 = xint[row*3+1], i2 = xint[row*3+2];
  float v;
  if (d < 28)        v = am[i0*28 + d];
  else if (d < 56)   v = el[i1*28 + (d-28)];
  else if (d < 84)   v = po[i2*28 + (d-56)];
  else {
    int o = d - 84;
    float x0 = xyz[row*3+0], x1 = xyz[row*3+1], x2 = xyz[row*3+2];
    v = fmaxf(xw[o*3+0]*x0 + xw[o*3+1]*x1 + xw[o*3+2]*x2 + xb[o], 0.0f);
  }
  emb[(size_t)row*256 + d] = v;
}

// ---------------- transpose weights: wt[k][j], k<2048 from w_ih, else w_hh ----------------
__global__ __launch_bounds__(256) void k_wt(const float* __restrict__ w_ih,
        const float* __restrict__ w_hh, float* __restrict__ wt) {
  __shared__ float t[32][33];
  int jt = blockIdx.x * 32, kt = blockIdx.y * 32;
  int tx = threadIdx.x & 31, ty = threadIdx.x >> 5;   // ty 0..7
#pragma unroll
  for (int i = 0; i < 4; i++) {
    int j = jt + ty + i*8;
    int k = kt + tx;
    float v = (k < 2048) ? w_ih[(size_t)j*2048 + k] : w_hh[(size_t)j*1024 + (k - 2048)];
    t[ty + i*8][tx] = v;
  }
  __syncthreads();
#pragma unroll
  for (int i = 0; i < 4; i++) {
    int k = kt + ty + i*8;
    int j = jt + tx;
    wt[(size_t)k*4096 + j] = t[tx][ty + i*8];
  }
}

// ---------------- Wc[k][d] = sum_o att1_w[k][1024+o] * up_w[o][d] ----------------
__global__ void k_wc(const float* __restrict__ up_w, const float* __restrict__ att1w,
                     float* __restrict__ wc) {
  int k = blockIdx.x;       // 128
  int d = threadIdx.x;      // 256
  __shared__ float s[256];
  float acc = 0.0f;
  const float* arow = att1w + (size_t)k*2048 + 1024;
  for (int o0 = 0; o0 < 1024; o0 += 256) {
    __syncthreads();
    s[d] = arow[o0 + d];
    __syncthreads();
#pragma unroll 8
    for (int oi = 0; oi < 256; oi++) acc += up_w[(size_t)(o0+oi)*256 + d] * s[oi];
  }
  wc[k*256 + d] = acc;
}

// ---------------- bc[k] = sum_o up_b[o] * att1_w[k][1024+o] ----------------
__global__ void k_bc(const float* __restrict__ up_b, const float* __restrict__ att1w,
                     float* __restrict__ bc) {
  int k = threadIdx.x;  // 128
  float acc = 0.0f;
  for (int o = 0; o < 1024; o += 4) {
    const float4 a4 = *(const float4*)(att1w + (size_t)k*2048 + 1024 + o);
    acc += up_b[o]*a4.x + up_b[o+1]*a4.y + up_b[o+2]*a4.z + up_b[o+3]*a4.w;
  }
  bc[k] = acc;
}

// ---------------- fp32 GEMM: C[M,Nc] = A[M,K] * W[n][k]^T + bias ----------------
__global__ __launch_bounds__(256) void k_gemm(const float* __restrict__ A, int K,
        const float* __restrict__ W, int ldw, int woff,
        const float* __restrict__ bias, float* __restrict__ C, int Nc) {
  __shared__ float As[16][128];
  __shared__ float Bs[16][128];
  const int m0 = blockIdx.x * 128;
  const int n0 = blockIdx.y * 128;
  const int tid = threadIdx.x;
  const int tx = tid & 15, ty = tid >> 4;
  float acc[8][8];
#pragma unroll
  for (int i = 0; i < 8; i++)
#pragma unroll
    for (int j = 0; j < 8; j++) acc[i][j] = 0.0f;

  for (int kt = 0; kt < K; kt += 16) {
#pragma unroll
    for (int i = 0; i < 2; i++) {
      int s = tid + i*256;
      int r = s >> 2;
      int kq = (s & 3) * 4;
      float4 a4 = *(const float4*)(A + (size_t)(m0 + r)*K + kt + kq);
      As[kq+0][r] = a4.x; As[kq+1][r] = a4.y; As[kq+2][r] = a4.z; As[kq+3][r] = a4.w;
      float4 b4 = *(const float4*)(W + (size_t)(n0 + r)*ldw + woff + kt + kq);
      Bs[kq+0][r] = b4.x; Bs[kq+1][r] = b4.y; Bs[kq+2][r] = b4.z; Bs[kq+3][r] = b4.w;
    }
    __syncthreads();
#pragma unroll
    for (int kk = 0; kk < 16; kk++) {
      float4 a0 = *(const float4*)&As[kk][ty*4];
      float4 a1 = *(const float4*)&As[kk][64 + ty*4];
      float4 b0 = *(const float4*)&Bs[kk][tx*4];
      float4 b1 = *(const float4*)&Bs[kk][64 + tx*4];
      float av[8] = {a0.x,a0.y,a0.z,a0.w,a1.x,a1.y,a1.z,a1.w};
      float bv[8] = {b0.x,b0.y,b0.z,b0.w,b1.x,b1.y,b1.z,b1.w};
#pragma unroll
      for (int i = 0; i < 8; i++)
#pragma unroll
        for (int j = 0; j < 8; j++) acc[i][j] += av[i]*bv[j];
    }
    __syncthreads();
  }
#pragma unroll
  for (int rh = 0; rh < 2; rh++)
#pragma unroll
    for (int i = 0; i < 4; i++) {
      int row = m0 + rh*64 + ty*4 + i;
#pragma unroll
      for (int ch = 0; ch < 2; ch++) {
        int col = n0 + ch*64 + tx*4;
        float4 o;
        o.x = acc[rh*4+i][ch*4+0];
        o.y = acc[rh*4+i][ch*4+1];
        o.z = acc[rh*4+i][ch*4+2];
        o.w = acc[rh*4+i][ch*4+3];
        if (bias) { o.x += bias[col]; o.y += bias[col+1]; o.z += bias[col+2]; o.w += bias[col+3]; }
        *(float4*)(C + (size_t)row*Nc + col) = o;
      }
    }
}

// ---------------- zero h,c ----------------
__global__ void k_zero(float* __restrict__ h, float* __restrict__ c) {
  int i = blockIdx.x * 256 + threadIdx.x;
  h[i] = 0.0f; c[i] = 0.0f;
}

// ---------------- gates partials: gp[ks][b][j] over transposed weights ----------------
__global__ __launch_bounds__(256) void k_gates(const float* __restrict__ P, const float* __restrict__ h,
        const float* __restrict__ wt, float* __restrict__ gp) {
  __shared__ float Xs[32][KCH];
  int jb = blockIdx.x;               // 0..15
  int ks = blockIdx.y;               // 0..23
  int tid = threadIdx.x;
  int kglob = ks * KCH;
  const float* src; int soff;
  if (ks < 8)       { src = P; soff = kglob; }
  else if (ks < 16) { src = h; soff = kglob - 1024; }
  else              { src = h; soff = kglob - 2048; }
#pragma unroll
  for (int i = 0; i < 4; i++) {
    int s = tid + i*256;             // float4 idx 0..1023
    int b = s >> 5;
    int k4 = s & 31;
    *(float4*)&Xs[b][k4*4] = *(const float4*)(src + b*1024 + soff + k4*4);
  }
  __syncthreads();

  int j = jb*256 + tid;
  const float* wr = wt + (size_t)kglob*4096 + j;
  float acc[32];
#pragma unroll
  for (int b = 0; b < 32; b++) acc[b] = 0.0f;

  for (int kk4 = 0; kk4 < KCH/4; kk4++) {
    float w0 = wr[(size_t)(kk4*4+0)*4096];
    float w1 = wr[(size_t)(kk4*4+1)*4096];
    float w2 = wr[(size_t)(kk4*4+2)*4096];
    float w3 = wr[(size_t)(kk4*4+3)*4096];
#pragma unroll
    for (int b = 0; b < 32; b++) {
      float4 x4 = *(const float4*)&Xs[b][kk4*4];
      acc[b] += w0*x4.x + w1*x4.y + w2*x4.z + w3*x4.w;
    }
  }
#pragma unroll
  for (int b = 0; b < 32; b++) gp[((size_t)ks*32 + b)*4096 + j] = acc[b];
}

// ---------------- reduce gates + LSTM cell ----------------
__global__ __launch_bounds__(256) void k_lstm(const float* __restrict__ gp,
        const float* __restrict__ b_ih, const float* __restrict__ b_hh,
        float* __restrict__ c, float* __restrict__ h) {
  int blk = blockIdx.x;            // 128 = b(32) x dch(4)
  int b = blk >> 2, dch = blk & 3;
  int d = dch*256 + threadIdx.x;
  float gi = b_ih[d]        + b_hh[d];
  float gf = b_ih[1024 + d] + b_hh[1024 + d];
  float gg = b_ih[2048 + d] + b_hh[2048 + d];
  float go = b_ih[3072 + d] + b_hh[3072 + d];
#pragma unroll 4
  for (int ks = 0; ks < KS; ks++) {
    const float* base = gp + ((size_t)ks*32 + b)*4096;
    gi += base[d]; gf += base[1024 + d]; gg += base[2048 + d]; go += base[3072 + d];
  }
  float cn = sigmoidf(gf)*c[b*1024 + d] + sigmoidf(gi)*tanhf(gg);
  c[b*1024 + d] = cn;
  h[b*1024 + d] = sigmoidf(go)*tanhf(cn);
}

// ---------------- ra[b][k] = h[b] . att1_w[k][:1024] ----------------
__global__ void k_ra(const float* __restrict__ h, const float* __restrict__ att1w,
                     float* __restrict__ ra) {
  int b = blockIdx.x;    // 32
  int t = threadIdx.x;   // 128
  __shared__ float hs[1024];
  *(float4*)&hs[t*8]     = *(const float4*)(h + b*1024 + t*8);
  *(float4*)&hs[t*8 + 4] = *(const float4*)(h + b*1024 + t*8 + 4);
  __syncthreads();
  float acc = 0.0f;
  const float* wr = att1w + (size_t)t*2048;
  for (int d = 0; d < 1024; d += 4) {
    float4 w4 = *(const float4*)(wr + d);
    acc += w4.x*hs[d] + w4.y*hs[d+1] + w4.z*hs[d+2] + w4.w*hs[d+3];
  }
  ra[b*128 + t] = acc;
}

// ---------------- logits[b][n] from xa ----------------
__global__ void k_logits(const float* __restrict__ xa, const float* __restrict__ ra,
                         const float* __restrict__ att1b, const float* __restrict__ att2w,
                         const float* __restrict__ att2b, float* __restrict__ lg) {
  int blk = blockIdx.x;            // 128
  int t = threadIdx.x;             // 256
  int row = blk*256 + t;
  int b = blk >> 2;
  __shared__ float rb[128], w2[128];
  if (t < 128) { rb[t] = ra[b*128 + t] + att1b[t]; w2[t] = att2w[t]; }
  __syncthreads();
  float acc = att2b[0];
  const float* xr = xa + (size_t)row*128;
  for (int k = 0; k < 128; k += 4) {
    float4 v = *(const float4*)(xr + k);
    acc += fmaxf(v.x + rb[k+0], 0.0f)*w2[k+0]
         + fmaxf(v.y + rb[k+1], 0.0f)*w2[k+1]
         + fmaxf(v.z + rb[k+2], 0.0f)*w2[k+2]
         + fmaxf(v.w + rb[k+3], 0.0f)*w2[k+3];
  }
  lg[row] = acc;
}

// ---------------- pooled emb partials: pp[nch][b][d]; lg==nullptr -> uniform ----------------
__global__ void k_poolemb(const float* __restrict__ emb, const float* __restrict__ lg,
                          float* __restrict__ pp) {
  int b = blockIdx.x >> 3, nch = blockIdx.x & 7;
  int t = threadIdx.x;             // 256 (=d)
  int n0 = nch*128;
  __shared__ float ws[128];
  __shared__ float red[256];
  if (lg) {
    float mx = -1e30f;
#pragma unroll
    for (int i = 0; i < 4; i++) mx = fmaxf(mx, lg[b*1024 + t + i*256]);
    red[t] = mx; __syncthreads();
    for (int s = 128; s > 0; s >>= 1) { if (t < s) red[t] = fmaxf(red[t], red[t+s]); __syncthreads(); }
    float m = red[0]; __syncthreads();
    float sum = 0.0f;
#pragma unroll
    for (int i = 0; i < 4; i++) sum += expf(lg[b*1024 + t + i*256] - m);
    red[t] = sum; __syncthreads();
    for (int s = 128; s > 0; s >>= 1) { if (t < s) red[t] += red[t+s]; __syncthreads(); }
    float inv = 1.0f / red[0];
    if (t < 128) ws[t] = expf(lg[b*1024 + n0 + t] - m) * inv;
  } else {
    if (t < 128) ws[t] = 1.0f;
  }
  __syncthreads();
  float acc = 0.0f;
  const float* eb = emb + (size_t)(b*1024 + n0)*256 + t;
  for (int n = 0; n < 128; n++) acc += ws[n] * eb[(size_t)n*256];
  pp[(size_t)(nch*32 + b)*256 + t] = acc;
}

// ---------------- reduce pool partials -> pe[b][d] ----------------
__global__ void k_pool2(const float* __restrict__ pp, float* __restrict__ pe, float scale) {
  int b = blockIdx.x, d = threadIdx.x;   // 32 x 256
  float s = 0.0f;
#pragma unroll
  for (int p = 0; p < 8; p++) s += pp[(size_t)(p*32 + b)*256 + d];
  pe[b*256 + d] = s * scale;
}

// ---------------- P[b][o] = pe[b] . up_w[o] + up_b[o] ----------------
__global__ __launch_bounds__(256) void k_pgemm(const float* __restrict__ pe,
        const float* __restrict__ up_w, const float* __restrict__ up_b,
        float* __restrict__ P) {
  int o0 = blockIdx.x * 8;           // 128 blocks
  int t = threadIdx.x;
  __shared__ float wsm[8][256];
  __shared__ float pes[32][257];
#pragma unroll
  for (int i = 0; i < 2; i++) {
    int idx = t + i*256;             // float4 idx 0..511 covering 8x256
    int row = idx >> 6, c4 = idx & 63;
    *(float4*)&wsm[row][c4*4] = *(const float4*)(up_w + (size_t)(o0 + row)*256 + c4*4);
  }
#pragma unroll
  for (int i = 0; i < 8; i++) {
    int idx = t + i*256;             // float4 idx 0..2047 covering 32x256
    int b = idx >> 6, c4 = idx & 63;
    float4 v = *(const float4*)(pe + (size_t)b*256 + c4*4);
    pes[b][c4*4+0] = v.x; pes[b][c4*4+1] = v.y; pes[b][c4*4+2] = v.z; pes[b][c4*4+3] = v.w;
  }
  __syncthreads();
  int b = t & 31, ol = t >> 5;
  float acc = up_b[o0 + ol];
  for (int d = 0; d < 256; d += 4) {
    float4 w4 = *(const float4*)&wsm[ol][d];
    acc += w4.x*pes[b][d] + w4.y*pes[b][d+1] + w4.z*pes[b][d+2] + w4.w*pes[b][d+3];
  }
  P[b*1024 + o0 + ol] = acc;
}

// ---------------- final energy ----------------
__global__ void k_out(const float* __restrict__ c, const float* __restrict__ ew,
                      const float* __restrict__ eb, float* __restrict__ out) {
  int b = blockIdx.x, t = threadIdx.x;   // 32 x 64
  float acc = 0.0f;
  for (int d = t; d < 1024; d += 64) acc += c[b*1024 + d] * ew[d];
  for (int off = 32; off > 0; off >>= 1) acc += __shfl_down(acc, off, 64);
  if (t == 0) out[b] = acc + eb[0];
}

extern "C" void kernel_launch(void* const* d_in, const int* in_sizes, int n_in,
                              void* d_out, int out_size, void* d_ws, size_t ws_size,
                              hipStream_t stream) {
  const int*   x_int  = (const int*)d_in[0];
  const float* x_xyz  = (const float*)d_in[1];
  const float* am     = (const float*)d_in[2];
  const float* el     = (const float*)d_in[3];
  const float* po     = (const float*)d_in[4];
  const float* xyz_w  = (const float*)d_in[5];
  const float* xyz_b  = (const float*)d_in[6];
  const float* up_w   = (const float*)d_in[7];
  const float* up_b   = (const float*)d_in[8];
  const float* w_ih   = (const float*)d_in[9];
  const float* w_hh   = (const float*)d_in[10];
  const float* b_ih   = (const float*)d_in[11];
  const float* b_hh   = (const float*)d_in[12];
  const float* att1_w = (const float*)d_in[13];
  const float* att1_b = (const float*)d_in[14];
  const float* att2_w = (const float*)d_in[15];
  const float* att2_b = (const float*)d_in[16];
  const float* en_w   = (const float*)d_in[17];
  const float* en_b   = (const float*)d_in[18];
  float* out = (float*)d_out;

  char* ws = (char*)d_ws;
  size_t off = 0;
  auto alloc = [&](size_t bytes) { void* p = ws + off; off += (bytes + 255) & ~(size_t)255; return p; };
  float* emb = (float*)alloc((size_t)BN*256*4);        // 33.6 MB
  float* wt  = (float*)alloc((size_t)3072*4096*4);     // 50.3 MB
  float* xa  = (float*)alloc((size_t)BN*128*4);        // 16.8 MB
  float* wc  = (float*)alloc((size_t)128*256*4);
  float* bc  = (float*)alloc((size_t)128*4);
  float* gp  = (float*)alloc((size_t)KS*32*4096*4);    // 12.6 MB
  float* pp  = (float*)alloc((size_t)8*32*256*4);
  float* pe  = (float*)alloc((size_t)32*256*4);
  float* P   = (float*)alloc((size_t)32*1024*4);
  float* h   = (float*)alloc((size_t)32*1024*4);
  float* c   = (float*)alloc((size_t)32*1024*4);
  float* ra  = (float*)alloc((size_t)32*128*4);
  float* lg  = (float*)alloc((size_t)32*1024*4);
  (void)ws_size; (void)in_sizes; (void)n_in; (void)out_size;

  k_zero<<<128, 256, 0, stream>>>(h, c);
  k_emb<<<BN, 256, 0, stream>>>(x_int, x_xyz, am, el, po, xyz_w, xyz_b, emb);
  k_wt<<<dim3(128, 96), 256, 0, stream>>>(w_ih, w_hh, wt);
  k_wc<<<128, 256, 0, stream>>>(up_w, att1_w, wc);
  k_bc<<<1, 128, 0, stream>>>(up_b, att1_w, bc);
  // xa = emb @ wc^T + bc   (M=32768, K=256, N=128)
  k_gemm<<<dim3(BN/128, 1), 256, 0, stream>>>(emb, 256, wc, 256, 0, bc, xa, 128);
  // P0 = mean path
  k_poolemb<<<256, 256, 0, stream>>>(emb, nullptr, pp);
  k_pool2<<<32, 256, 0, stream>>>(pp, pe, 1.0f/1024.0f);
  k_pgemm<<<128, 256, 0, stream>>>(pe, up_w, up_b, P);

  for (int step = 0; step < 6; step++) {
    k_gates<<<dim3(16, KS), 256, 0, stream>>>(P, h, wt, gp);
    k_lstm<<<128, 256, 0, stream>>>(gp, b_ih, b_hh, c, h);
    if (step < 5) {  // last step's attention output is unused
      k_ra<<<32, 128, 0, stream>>>(h, att1_w, ra);
      k_logits<<<128, 256, 0, stream>>>(xa, ra, att1_b, att2_w, att2_b, lg);
      k_poolemb<<<256, 256, 0, stream>>>(emb, lg, pp);
      k_pool2<<<32, 256, 0, stream>>>(pp, pe, 1.0f);
      k_pgemm<<<128, 256, 0, stream>>>(pe, up_w, up_b, P);
    }
  }
  k_out<<<32, 64, 0, stream>>>(c, en_w, en_b, out);
}